// Round 9
// baseline (31.069 us; speedup 1.0000x reference)
//
#include <hip/hip_runtime.h>

#define NEG_INF_F (-10000.0f)
#define EPS_F (1e-8f)

typedef float f4 __attribute__((ext_vector_type(4)));

// ---------------------------------------------------------------------------
// Kernel A: one wave per 8 consecutive rows, 3-deep rotating prefetch buffer.
// While row r is reduced, rows r+1 and r+2 are in flight (8 KB/wave
// outstanding -> ~2 reduce-chains of latency cover vs ~1 for the r5 depth-2
// version). Half the prologue/epilogue transitions of r5 (4096 waves, still
// 16/CU). All buffer indices compile-time via full unroll. Per-row math
// identical to r5 => bit-identical results.
// ---------------------------------------------------------------------------
template <int H>
__global__ __launch_bounds__(256) void row_stats_pipe8(
    const float* __restrict__ seq, const int* __restrict__ idxs,
    float* __restrict__ d1, float* __restrict__ d2, float* __restrict__ n2,
    int S, int nrows) {
  constexpr int NF4 = H / 4;   // f4 per row
  constexpr int C = H / 256;   // f4 loads per lane per row (4 for H=1024)
  constexpr int R = 8;         // rows per wave
  int wave = blockIdx.x * 4 + (threadIdx.x >> 6);
  int lane = threadIdx.x & 63;
  int row0 = wave * R;
  if (row0 >= nrows) return;

  int b = row0 / S;            // S % 8 == 0 -> all R rows in one batch
  int sep0 = idxs[2 * b];

  const f4* base = reinterpret_cast<const f4*>(seq);
  const f4* q1p = base + ((size_t)b * S + 1) * NF4 + lane;
  const f4* q2p = base + ((size_t)b * S + (sep0 - 1)) * NF4 + lane;
  const f4* rp = base + (size_t)row0 * NF4 + lane;

  f4 q1f[C], q2f[C], x[3][C];
  #pragma unroll
  for (int i = 0; i < C; ++i) q1f[i] = q1p[i * 64];
  #pragma unroll
  for (int i = 0; i < C; ++i) q2f[i] = q2p[i * 64];
  #pragma unroll
  for (int i = 0; i < C; ++i) x[0][i] = rp[i * 64];
  #pragma unroll
  for (int i = 0; i < C; ++i) x[1][i] = rp[NF4 + i * 64];

  #pragma unroll
  for (int r = 0; r < R; ++r) {
    // Prefetch row r+2 into the buffer vacated by row r-1. Compute of row r
    // waits on loads issued two reduce-chains ago -> HBM latency covered.
    if (r + 2 < R) {
      const f4* np = rp + (size_t)(r + 2) * NF4;
      #pragma unroll
      for (int i = 0; i < C; ++i) x[(r + 2) % 3][i] = np[i * 64];
    }
    float s1 = 0.f, s2 = 0.f, sn = 0.f;
    #pragma unroll
    for (int i = 0; i < C; ++i) {
      f4 v = x[r % 3][i];
      s1 += v[0] * q1f[i][0] + v[1] * q1f[i][1] + v[2] * q1f[i][2] + v[3] * q1f[i][3];
      s2 += v[0] * q2f[i][0] + v[1] * q2f[i][1] + v[2] * q2f[i][2] + v[3] * q2f[i][3];
      sn += v[0] * v[0] + v[1] * v[1] + v[2] * v[2] + v[3] * v[3];
    }
    #pragma unroll
    for (int off = 32; off >= 1; off >>= 1) {
      s1 += __shfl_xor(s1, off, 64);
      s2 += __shfl_xor(s2, off, 64);
      sn += __shfl_xor(sn, off, 64);
    }
    if (lane == 0) {
      d1[row0 + r] = s1;
      d2[row0 + r] = s2;
      n2[row0 + r] = sn;
    }
  }
}

// Generic fallback (runtime H): one wave per row.
__global__ __launch_bounds__(256) void row_stats_kernel(
    const float* __restrict__ seq, const int* __restrict__ idxs,
    float* __restrict__ d1, float* __restrict__ d2, float* __restrict__ n2,
    int B, int S, int H) {
  int gtid = blockIdx.x * blockDim.x + threadIdx.x;
  int row = gtid >> 6;
  int lane = threadIdx.x & 63;
  int nrows = B * S;
  if (row >= nrows) return;

  int b = row / S;
  int sep0 = idxs[b * 2 + 0];

  const float* rowp = seq + (size_t)row * H;
  const float* q1p = seq + ((size_t)b * S + 1) * H;
  const float* q2p = seq + ((size_t)b * S + (sep0 - 1)) * H;

  float s1 = 0.f, s2 = 0.f, sn = 0.f;
  for (int h = lane * 4; h < H; h += 64 * 4) {
    float4 x = *reinterpret_cast<const float4*>(rowp + h);
    float4 a = *reinterpret_cast<const float4*>(q1p + h);
    float4 c = *reinterpret_cast<const float4*>(q2p + h);
    s1 += x.x * a.x + x.y * a.y + x.z * a.z + x.w * a.w;
    s2 += x.x * c.x + x.y * c.y + x.z * c.z + x.w * c.w;
    sn += x.x * x.x + x.y * x.y + x.z * x.z + x.w * x.w;
  }
  #pragma unroll
  for (int off = 32; off >= 1; off >>= 1) {
    s1 += __shfl_xor(s1, off, 64);
    s2 += __shfl_xor(s2, off, 64);
    sn += __shfl_xor(sn, off, 64);
  }
  if (lane == 0) {
    d1[row] = s1;
    d2[row] = s2;
    n2[row] = sn;
  }
}

// ---------------------------------------------------------------------------
// Kernel B (round-5 proven version): one thread per (b,s), L=32 full unroll,
// rsqrt. First-occurrence argmax via strict '>' (matches jnp.argmax).
// ---------------------------------------------------------------------------
template <int L>
__global__ __launch_bounds__(64) void window_max_fast(
    const float* __restrict__ d1, const float* __restrict__ d2,
    const float* __restrict__ n2, const int* __restrict__ idxs,
    float* __restrict__ out, int S, int nrows) {
  int t = blockIdx.x * 64 + threadIdx.x;
  if (t >= nrows) return;
  int b = t / S;
  int s = t - b * S;

  int sep0 = idxs[b * 2 + 0];
  int sep1 = idxs[b * 2 + 1];

  size_t bS = (size_t)b * S;
  float qn2 = n2[bS + 1] + n2[bS + (sep0 - 1)];
  float my_d1 = d1[t];
  float my_n2 = n2[t];

  const float* d2b = d2 + bS;
  const float* n2b = n2 + bS;

  float best = NEG_INF_F;
  int best_l = 0;
  #pragma unroll
  for (int l = 0; l < L; ++l) {
    int j = min(s + l, S - 1);
    float w2 = n2b[j];
    float v2 = d2b[j];
    float prod = (my_n2 + w2) * qn2;
    float sim = (my_d1 + v2) * __frsqrt_rn(fmaxf(prod, EPS_F * EPS_F));
    sim = (s + l < sep1) ? sim : NEG_INF_F;
    if (sim > best) { best = sim; best_l = l; }
  }

  bool valid_i = (s > sep0) && (s < sep1);
  out[t] = valid_i ? best : NEG_INF_F;
  out[nrows + t] = valid_i ? (float)(s + best_l) : -1.0f;
}

extern "C" void kernel_launch(void* const* d_in, const int* in_sizes, int n_in,
                              void* d_out, int out_size, void* d_ws, size_t ws_size,
                              hipStream_t stream) {
  const float* seq = (const float*)d_in[0];
  const int* idxs = (const int*)d_in[1];
  const int* pL = (const int*)d_in[2];

  int B = in_sizes[1] / 2;
  int S = out_size / (2 * B);
  int H = (int)((long long)in_sizes[0] / ((long long)B * S));
  int nrows = B * S;

  float* d1 = (float*)d_ws;
  float* d2 = d1 + nrows;
  float* n2 = d2 + nrows;

  if (H == 1024 && (S % 8) == 0 && (nrows % 32) == 0) {
    // 8 rows per wave (3-deep pipeline), 4 waves per block -> 32 rows/block.
    int gridA = nrows / 32;
    row_stats_pipe8<1024><<<gridA, 256, 0, stream>>>(seq, idxs, d1, d2, n2, S,
                                                     nrows);
  } else {
    int gridA = (nrows + 3) / 4;
    row_stats_kernel<<<gridA, 256, 0, stream>>>(seq, idxs, d1, d2, n2, B, S, H);
  }

  int gridB = (nrows + 63) / 64;
  window_max_fast<32><<<gridB, 64, 0, stream>>>(d1, d2, n2, idxs,
                                                (float*)d_out, S, nrows);
  (void)pL;
}

// Round 10
// 28.865 us; speedup vs baseline: 1.0764x; 1.0764x over previous
//
#include <hip/hip_runtime.h>

#define NEG_INF_F (-10000.0f)
#define EPS_F (1e-8f)

typedef float f4 __attribute__((ext_vector_type(4)));

// ---------------------------------------------------------------------------
// Kernel A: round-5 proven structure (one wave per 4 consecutive rows,
// depth-2 register pipeline, q1/q2 hoisted per wave, plain loads) PLUS
// device-side dead-row skip: a wave whose 4 rows are all outside
//   {1, sep0-1}  ∪  (sep0, sep1+30]
// returns before issuing any row loads. Stats of skipped rows feed only
// masked-out outputs in B (which overwrites them with constants), so valid
// outputs are bit-identical to round 5.
// ---------------------------------------------------------------------------
template <int H>
__global__ __launch_bounds__(256) void row_stats_pipe(
    const float* __restrict__ seq, const int* __restrict__ idxs,
    float* __restrict__ d1, float* __restrict__ d2, float* __restrict__ n2,
    int S, int nrows) {
  constexpr int NF4 = H / 4;   // f4 per row
  constexpr int C = H / 256;   // f4 loads per lane per row (4 for H=1024)
  constexpr int R = 4;         // rows per wave (pipelined)
  int wave = blockIdx.x * 4 + (threadIdx.x >> 6);
  int lane = threadIdx.x & 63;
  int row0 = wave * R;
  if (row0 >= nrows) return;

  int b = row0 / S;            // S % 4 == 0 -> all R rows in one batch
  int sep0 = idxs[2 * b];
  int sep1 = idxs[2 * b + 1];

  // Dead-row skip. Local row range of this wave: [s_lo, s_hi].
  int s_lo = row0 - b * S;
  int s_hi = s_lo + R - 1;
  bool contains_q = (1 >= s_lo && 1 <= s_hi) ||
                    (sep0 - 1 >= s_lo && sep0 - 1 <= s_hi);
  bool in_window = (s_hi > sep0) && (s_lo <= sep1 + 30);
  if (!(contains_q || in_window)) return;

  const f4* base = reinterpret_cast<const f4*>(seq);
  const f4* q1p = base + ((size_t)b * S + 1) * NF4 + lane;
  const f4* q2p = base + ((size_t)b * S + (sep0 - 1)) * NF4 + lane;
  const f4* rp = base + (size_t)row0 * NF4 + lane;

  f4 q1f[C], q2f[C], x[2][C];
  #pragma unroll
  for (int i = 0; i < C; ++i) q1f[i] = q1p[i * 64];
  #pragma unroll
  for (int i = 0; i < C; ++i) q2f[i] = q2p[i * 64];
  #pragma unroll
  for (int i = 0; i < C; ++i) x[0][i] = rp[i * 64];

  #pragma unroll
  for (int r = 0; r < R; ++r) {
    if (r + 1 < R) {
      const f4* np = rp + (size_t)(r + 1) * NF4;
      #pragma unroll
      for (int i = 0; i < C; ++i) x[(r + 1) & 1][i] = np[i * 64];
    }
    float s1 = 0.f, s2 = 0.f, sn = 0.f;
    #pragma unroll
    for (int i = 0; i < C; ++i) {
      f4 v = x[r & 1][i];
      s1 += v[0] * q1f[i][0] + v[1] * q1f[i][1] + v[2] * q1f[i][2] + v[3] * q1f[i][3];
      s2 += v[0] * q2f[i][0] + v[1] * q2f[i][1] + v[2] * q2f[i][2] + v[3] * q2f[i][3];
      sn += v[0] * v[0] + v[1] * v[1] + v[2] * v[2] + v[3] * v[3];
    }
    #pragma unroll
    for (int off = 32; off >= 1; off >>= 1) {
      s1 += __shfl_xor(s1, off, 64);
      s2 += __shfl_xor(s2, off, 64);
      sn += __shfl_xor(sn, off, 64);
    }
    if (lane == 0) {
      d1[row0 + r] = s1;
      d2[row0 + r] = s2;
      n2[row0 + r] = sn;
    }
  }
}

// Generic fallback (runtime H): one wave per row, no skip (always correct).
__global__ __launch_bounds__(256) void row_stats_kernel(
    const float* __restrict__ seq, const int* __restrict__ idxs,
    float* __restrict__ d1, float* __restrict__ d2, float* __restrict__ n2,
    int B, int S, int H) {
  int gtid = blockIdx.x * blockDim.x + threadIdx.x;
  int row = gtid >> 6;
  int lane = threadIdx.x & 63;
  int nrows = B * S;
  if (row >= nrows) return;

  int b = row / S;
  int sep0 = idxs[b * 2 + 0];

  const float* rowp = seq + (size_t)row * H;
  const float* q1p = seq + ((size_t)b * S + 1) * H;
  const float* q2p = seq + ((size_t)b * S + (sep0 - 1)) * H;

  float s1 = 0.f, s2 = 0.f, sn = 0.f;
  for (int h = lane * 4; h < H; h += 64 * 4) {
    float4 x = *reinterpret_cast<const float4*>(rowp + h);
    float4 a = *reinterpret_cast<const float4*>(q1p + h);
    float4 c = *reinterpret_cast<const float4*>(q2p + h);
    s1 += x.x * a.x + x.y * a.y + x.z * a.z + x.w * a.w;
    s2 += x.x * c.x + x.y * c.y + x.z * c.z + x.w * c.w;
    sn += x.x * x.x + x.y * x.y + x.z * x.z + x.w * x.w;
  }
  #pragma unroll
  for (int off = 32; off >= 1; off >>= 1) {
    s1 += __shfl_xor(s1, off, 64);
    s2 += __shfl_xor(s2, off, 64);
    sn += __shfl_xor(sn, off, 64);
  }
  if (lane == 0) {
    d1[row] = s1;
    d2[row] = s2;
    n2[row] = sn;
  }
}

// ---------------------------------------------------------------------------
// Kernel B: one thread per (b,s), L=32 full unroll, rsqrt. Invalid rows
// early-exit with their constant outputs (skipping the window loop entirely;
// also guarantees stale stats of skipped A-rows never influence results).
// First-occurrence argmax via strict '>' (matches jnp.argmax).
// ---------------------------------------------------------------------------
template <int L>
__global__ __launch_bounds__(64) void window_max_fast(
    const float* __restrict__ d1, const float* __restrict__ d2,
    const float* __restrict__ n2, const int* __restrict__ idxs,
    float* __restrict__ out, int S, int nrows) {
  int t = blockIdx.x * 64 + threadIdx.x;
  if (t >= nrows) return;
  int b = t / S;
  int s = t - b * S;

  int sep0 = idxs[b * 2 + 0];
  int sep1 = idxs[b * 2 + 1];

  bool valid_i = (s > sep0) && (s < sep1);
  if (!valid_i) {
    out[t] = NEG_INF_F;
    out[nrows + t] = -1.0f;
    return;
  }

  size_t bS = (size_t)b * S;
  float qn2 = n2[bS + 1] + n2[bS + (sep0 - 1)];
  float my_d1 = d1[t];
  float my_n2 = n2[t];

  const float* d2b = d2 + bS;
  const float* n2b = n2 + bS;

  float best = NEG_INF_F;
  int best_l = 0;
  #pragma unroll
  for (int l = 0; l < L; ++l) {
    int j = min(s + l, S - 1);
    float w2 = n2b[j];
    float v2 = d2b[j];
    float prod = (my_n2 + w2) * qn2;
    float sim = (my_d1 + v2) * __frsqrt_rn(fmaxf(prod, EPS_F * EPS_F));
    sim = (s + l < sep1) ? sim : NEG_INF_F;
    if (sim > best) { best = sim; best_l = l; }
  }

  out[t] = best;
  out[nrows + t] = (float)(s + best_l);
}

extern "C" void kernel_launch(void* const* d_in, const int* in_sizes, int n_in,
                              void* d_out, int out_size, void* d_ws, size_t ws_size,
                              hipStream_t stream) {
  const float* seq = (const float*)d_in[0];
  const int* idxs = (const int*)d_in[1];
  const int* pL = (const int*)d_in[2];

  int B = in_sizes[1] / 2;
  int S = out_size / (2 * B);
  int H = (int)((long long)in_sizes[0] / ((long long)B * S));
  int nrows = B * S;

  float* d1 = (float*)d_ws;
  float* d2 = d1 + nrows;
  float* n2 = d2 + nrows;

  if (H == 1024 && (S % 4) == 0 && (nrows % 16) == 0) {
    // 4 rows per wave (pipelined), 4 waves per block -> 16 rows per block.
    int gridA = nrows / 16;
    row_stats_pipe<1024><<<gridA, 256, 0, stream>>>(seq, idxs, d1, d2, n2, S,
                                                    nrows);
  } else {
    int gridA = (nrows + 3) / 4;
    row_stats_kernel<<<gridA, 256, 0, stream>>>(seq, idxs, d1, d2, n2, B, S, H);
  }

  int gridB = (nrows + 63) / 64;
  window_max_fast<32><<<gridB, 64, 0, stream>>>(d1, d2, n2, idxs,
                                                (float*)d_out, S, nrows);
  (void)pL;
}